// Round 1
// baseline (312.462 us; speedup 1.0000x reference)
//
#include <hip/hip_runtime.h>

// Clifford Cl(3,0) geometric product. Pure streaming op: 268 MB read + 134 MB
// write, no reuse -> target is the HBM roofline (~64 us @ 6.3 TB/s).
//
// R2 theory: the LDS-staged version (305 us ~ 1.3 TB/s) was barrier-bound:
// 3x __syncthreads per 16 KB tile forces a vmcnt(0) drain each time, so each
// wave never has more than 4 KB of loads in flight against ~900-cycle HBM
// latency. There is NO data reuse here, so LDS buys nothing except lane-dense
// VMEM -- which a lane-pair __shfl_xor gives for free:
//   float4 element idx is half of multivector idx>>1; lanes 2k and 2k+1
//   exchange halves via __shfl_xor(x,1) (DPP quad-perm, no LDS, no barrier),
//   each lane computes the product, stores its own half. Every global load
//   and store instruction is lane-dense (64 lanes x 16 B contiguous).
// Grid-stride at 2048 blocks = 8 resident blocks/CU; no barriers anywhere, so
// waves stream with maximal outstanding loads.

__global__ __launch_bounds__(256) void CliffordProduct_85452669321821_kernel(
    const float4* __restrict__ a, const float4* __restrict__ b,
    float4* __restrict__ out, int n4) {
    const int stride = gridDim.x * blockDim.x;
    const bool hi = (threadIdx.x & 1);  // odd lane holds the high half (e4..e7)

    for (int idx = blockIdx.x * blockDim.x + threadIdx.x; idx < n4;
         idx += stride) {
        // Dense loads: lane i -> byte 16*i of the wave's 1 KiB segment.
        float4 va = a[idx];
        float4 vb = b[idx];

        // Partner's half via xor-1 shuffle (pairs never straddle the wave,
        // and n4 is even so both lanes of a pair share the bounds check).
        float4 pa, pb;
        pa.x = __shfl_xor(va.x, 1);
        pa.y = __shfl_xor(va.y, 1);
        pa.z = __shfl_xor(va.z, 1);
        pa.w = __shfl_xor(va.w, 1);
        pb.x = __shfl_xor(vb.x, 1);
        pb.y = __shfl_xor(vb.y, 1);
        pb.z = __shfl_xor(vb.z, 1);
        pb.w = __shfl_xor(vb.w, 1);

        // Assemble the full multivector (uniform code, cndmask selects).
        float A0 = hi ? pa.x : va.x, A1 = hi ? pa.y : va.y;
        float A2 = hi ? pa.z : va.z, A3 = hi ? pa.w : va.w;
        float A4 = hi ? va.x : pa.x, A5 = hi ? va.y : pa.y;
        float A6 = hi ? va.z : pa.z, A7 = hi ? va.w : pa.w;
        float B0 = hi ? pb.x : vb.x, B1 = hi ? pb.y : vb.y;
        float B2 = hi ? pb.z : vb.z, B3 = hi ? pb.w : vb.w;
        float B4 = hi ? vb.x : pb.x, B5 = hi ? vb.y : pb.y;
        float B6 = hi ? vb.z : pb.z, B7 = hi ? vb.w : pb.w;

        // Full product (both lanes compute all 8; VALU is ~15% busy at the
        // BW roofline, so the duplicated arithmetic is free).
        float c0 = A0*B0 + A1*B1 + A2*B2 + A3*B3 - A4*B4 - A5*B5 - A6*B6 - A7*B7;
        float c1 = A0*B1 + A1*B0 - A2*B4 + A4*B2 - A3*B5 + A5*B3 - A6*B7 - A7*B6;
        float c2 = A0*B2 + A2*B0 + A1*B4 - A4*B1 - A3*B6 + A6*B3 + A5*B7 + A7*B5;
        float c3 = A0*B3 + A3*B0 + A1*B5 - A5*B1 + A2*B6 - A6*B2 - A4*B7 - A7*B4;
        float c4 = A0*B4 + A4*B0 + A1*B2 - A2*B1 - A5*B6 + A6*B5 + A3*B7 + A7*B3;
        float c5 = A0*B5 + A5*B0 + A1*B3 - A3*B1 + A4*B6 - A6*B4 - A2*B7 - A7*B2;
        float c6 = A0*B6 + A6*B0 + A2*B3 - A3*B2 - A4*B5 + A5*B4 + A1*B7 + A7*B1;
        float c7 = A0*B7 + A7*B0 + A1*B6 + A6*B1 - A2*B5 - A5*B2 + A3*B4 + A4*B3;

        // Dense stores: each lane writes its own half of the result.
        out[idx] = hi ? make_float4(c4, c5, c6, c7)
                      : make_float4(c0, c1, c2, c3);
    }
}

extern "C" void kernel_launch(void* const* d_in, const int* in_sizes, int n_in,
                              void* d_out, int out_size, void* d_ws, size_t ws_size,
                              hipStream_t stream) {
    const float4* a = (const float4*)d_in[0];
    const float4* b = (const float4*)d_in[1];
    float4* out = (float4*)d_out;
    int n4 = in_sizes[0] / 4;  // total float4 elements (2 per multivector)

    int blocks = (n4 + 255) / 256;
    if (blocks > 2048) blocks = 2048;  // 8 resident blocks/CU, grid-stride
    CliffordProduct_85452669321821_kernel<<<blocks, 256, 0, stream>>>(a, b, out, n4);
}